// Round 19
// baseline (3695.385 us; speedup 1.0000x reference)
//
#include <hip/hip_runtime.h>

typedef float v2f __attribute__((ext_vector_type(2)));
typedef float v4f __attribute__((ext_vector_type(4)));

constexpr int T  = 1024;
constexpr int B  = 32;
constexpr int I_ = 64;
constexpr int H  = 1024;
constexpr int OF = 64;
constexpr int OC = 8;
constexpr int NG = 8;    // groups (4 batches each)
constexpr int NM = 32;   // member WGs per group (32 rows each)
constexpr int CHK = 68;  // per-lane k-chunk (1088/16)
constexpr int CHP = 76;  // padded chunk stride (12*l16 mod 32 -> 2-way max, free)
constexpr int BSTR = 16 * CHP;               // 1216 floats per batch buffer
constexpr long long OUT1_OFF = (long long)T * B * OF;
constexpr long long OUT2_OFF = (long long)T * B * (OF + OC);
constexpr int RING_U64 = NG * 4 * 4 * 1024;  // [g][slot4][batch4][row] = 1 MB

// Agent-scope relaxed ops: global_{load,store} sc0 sc1 — bypass L1/L2,
// coherent at L3, fence-free. Proven medium (R2/R6/R10/R11/R14-R16).
// sc0-only polling livelocks (R4/R5/R7) — never used.
__device__ __forceinline__ void st_agent_f32(float* p, float v) {
  __hip_atomic_store(p, v, __ATOMIC_RELAXED, __HIP_MEMORY_SCOPE_AGENT);
}
__device__ __forceinline__ void st_agent_u64(unsigned long long* p,
                                             unsigned long long v) {
  __hip_atomic_store(p, v, __ATOMIC_RELAXED, __HIP_MEMORY_SCOPE_AGENT);
}
__device__ __forceinline__ unsigned long long
ld_agent_u64(const unsigned long long* p) {
  return __hip_atomic_load(p, __ATOMIC_RELAXED, __HIP_MEMORY_SCOPE_AGENT);
}

// ---------------------------------------------------------------------------
// Recurrence: 256 persistent WGs x 512 threads (1/CU).
// SYMMETRIC-SLACK PING-PONG (fixes the R11-R16 residual: in 2-batch
// ping-pong one handoff is stored at step end and consumed at step start —
// zero phases of slack; its stale probe cost ~0.4us/step):
//   group g = bid&7 owns batches [4g,4g+4); member m = bid>>3 owns rows
//   [32m,+32). Thread (jrel=tid>>4, l16=tid&15): row j=32m+jrel, k-chunk
//   [l16*68,+68), weights 34 v2f (i2h folded at k>=1024).
//   phase A(t): compute {0,1} step t (from lds[0],lds[1]);
//               probe {2,3}'s r_{t-1} (tag t, stored at END of B(t-1) —
//               sampled at q=11/17 of A's FMA loop = +0.4-0.5us, past the
//               ~0.35us visibility horizon) + x_t({2,3}); commit lds[2],[3].
//   phase B(t): compute {2,3} step t; probe {0,1}'s r_t (tag t+1, stored
//               end of A(t)) + x_{t+1}({0,1}); commit lds[0],[1].
// Per-phase compute is UNCHANGED from R16 (136 MAC, 34 ds_read_b128, 64
// packets/WG) — R12's phase-shrink mistake avoided. ONE sched_barrier per
// phase pins the probe issue (R14's dose; R17's multi-pin broke pipelining).
// Liveness: probes are the only waits, on unconditionally-stored monotone
// tags => R10-R16 induction. 4-slot ring, lead bound 2 < 4. lgkm-only
// barriers (R15/R16-proven). Ring zeroed per call (tags >= 1).
// ---------------------------------------------------------------------------
__global__ __launch_bounds__(512, 1) void rnn_recur(
    const float* __restrict__ input_sig, const float* __restrict__ rate0,
    const float* __restrict__ i2h_w, const float* __restrict__ i2h_b,
    const float* __restrict__ h2h_w, const float* __restrict__ h2h_b,
    float* __restrict__ rate_all, unsigned long long* __restrict__ ring)
{
  const int tid = threadIdx.x;
  const int bid = blockIdx.x;
  const int g   = bid & (NG - 1);
  const int m   = bid >> 3;
  const int l16 = tid & 15;
  const int jrel = tid >> 4;
  const int j   = m * 32 + jrel;
  const int bG  = g * 4;

  __shared__ float lds[4][BSTR];   // [batch][16 chunks x 76]; x at chunk-15 tail

  // ---- stationary weights: 34 v2f = 68 fp32/thread (halved vs R16)
  v2f w2[34];
#pragma unroll
  for (int q = 0; q < 34; ++q) {
    const int k = l16 * CHK + 2 * q;
    w2[q] = (k < H) ? *(const v2f*)(h2h_w + (long long)j * H + k)
                    : *(const v2f*)(i2h_w + (long long)j * I_ + (k - H));
  }
  const float bsum = h2h_b[j] + i2h_b[j];
  const int posj = (j / CHK) * CHP + (j % CHK);
  const int pos2 = ((2 * tid) / CHK) * CHP + (2 * tid) % CHK;  // even, no chunk-cross

  // ---- init: r_{-1} = rate0 and x_0 for all 4 batches (plain cached loads)
#pragma unroll
  for (int b = 0; b < 4; ++b) {
    float2 rv = *(const float2*)(rate0 + (long long)(bG + b) * H + 2 * tid);
    *(float2*)&lds[b][pos2] = rv;
  }
  if (tid < 64) {
    const int b = tid >> 4, xi = (tid & 15) * 4;
    float4 xv = *(const float4*)(input_sig + (long long)(bG + b) * I_ + xi);
    *(float4*)&lds[b][15 * CHP + 4 + xi] = xv;   // k=1024+xi -> chunk15 pos 4+xi
  }
  __syncthreads();

  unsigned long long* ringG = ring + (long long)g * (4 * 4 * 1024);

  // One phase: compute batches {blo,blo+1} at step t; probe batches
  // {pb,pb+1}'s tagged packets (ptag, pslot) + x_{xt}; commit to lds[pb..].
  auto phase = [&](int blo, int t, int pb, unsigned ptag, int pslot, int xt,
                   bool doP) {
    const float* R0 = &lds[blo][0];
    const float* R1 = &lds[blo + 1][0];
    const int kb = l16 * CHP;
    v2f a0 = {0.f, 0.f}, a1 = {0.f, 0.f};
#pragma unroll
    for (int q = 0; q < 11; ++q) {
      const v4f r0 = *(const v4f*)&R0[kb + 4 * q];
      const v4f r1 = *(const v4f*)&R1[kb + 4 * q];
      a0 = __builtin_elementwise_fma(w2[2 * q],
               __builtin_shufflevector(r0, r0, 0, 1), a0);
      a0 = __builtin_elementwise_fma(w2[2 * q + 1],
               __builtin_shufflevector(r0, r0, 2, 3), a0);
      a1 = __builtin_elementwise_fma(w2[2 * q],
               __builtin_shufflevector(r1, r1, 0, 1), a1);
      a1 = __builtin_elementwise_fma(w2[2 * q + 1],
               __builtin_shufflevector(r1, r1, 2, 3), a1);
    }
    // single fence: probe loads below cannot hoist above (issue ~2/3 into
    // the phase = ~0.4-0.5us after the producer stores they target)
    __builtin_amdgcn_sched_barrier(0);
    unsigned long long qa = 0, qb = 0, qc = 0, qd = 0;
    float4 xv;
    const unsigned long long* plo =
        &ringG[((long long)(pslot * 4 + pb) << 10) + 2 * tid];
    const unsigned long long* phi = plo + 1024;   // batch pb+1
    if (doP) {
      qa = ld_agent_u64(plo);
      qb = ld_agent_u64(plo + 1);
      qc = ld_agent_u64(phi);
      qd = ld_agent_u64(phi + 1);
      if (tid < 32) {
        const int xb = tid >> 4, xi = (tid & 15) * 4;
        xv = *(const float4*)(input_sig +
            ((long long)xt * B + bG + pb + xb) * I_ + xi);
      }
    }
#pragma unroll
    for (int q = 11; q < 17; ++q) {
      const v4f r0 = *(const v4f*)&R0[kb + 4 * q];
      const v4f r1 = *(const v4f*)&R1[kb + 4 * q];
      a0 = __builtin_elementwise_fma(w2[2 * q],
               __builtin_shufflevector(r0, r0, 0, 1), a0);
      a0 = __builtin_elementwise_fma(w2[2 * q + 1],
               __builtin_shufflevector(r0, r0, 2, 3), a0);
      a1 = __builtin_elementwise_fma(w2[2 * q],
               __builtin_shufflevector(r1, r1, 0, 1), a1);
      a1 = __builtin_elementwise_fma(w2[2 * q + 1],
               __builtin_shufflevector(r1, r1, 2, 3), a1);
    }
    // 16-lane fold, both batches: lanes 0 mod 16 -> blo sum, 8 mod 16 -> blo+1
    float s0 = a0.x + a0.y, s1 = a1.x + a1.y;
    const float t0 = __shfl_xor(s0, 8, 64);
    const float t1 = __shfl_xor(s1, 8, 64);
    float u = (l16 & 8) ? (s1 + t1) : (s0 + t0);
    u += __shfl_xor(u, 4, 64);
    u += __shfl_xor(u, 2, 64);
    u += __shfl_xor(u, 1, 64);
    if ((l16 & 7) == 0) {
      const int b = blo + (l16 >> 3);
      const float pre  = u + bsum;
      const float rold = lds[b][posj];
      const float rnew = 0.9f * rold + 0.1f * tanhf(pre);
      const unsigned long long pkt =
          ((unsigned long long)(unsigned)(t + 1) << 32) |
          (unsigned long long)__float_as_uint(rnew);
      st_agent_u64(&ringG[((long long)((t & 3) * 4 + b) << 10) + j], pkt);
      st_agent_f32(&rate_all[((long long)t * B + bG + b) * H + j], rnew);
    }
    if (doP) {
      while ((unsigned)(qa >> 32) != ptag || (unsigned)(qb >> 32) != ptag ||
             (unsigned)(qc >> 32) != ptag || (unsigned)(qd >> 32) != ptag) {
        qa = ld_agent_u64(plo);
        qb = ld_agent_u64(plo + 1);
        qc = ld_agent_u64(phi);
        qd = ld_agent_u64(phi + 1);
      }
      *(float2*)&lds[pb][pos2] = make_float2(
          __uint_as_float((unsigned)qa), __uint_as_float((unsigned)qb));
      *(float2*)&lds[pb + 1][pos2] = make_float2(
          __uint_as_float((unsigned)qc), __uint_as_float((unsigned)qd));
      if (tid < 32) {
        const int xb = tid >> 4, xi = (tid & 15) * 4;
        *(float4*)&lds[pb + xb][15 * CHP + 4 + xi] = xv;
      }
    }
  };

  for (int t = 0; t < T; ++t) {
    // phase A: compute {0,1}(t); probe {2,3} r_{t-1} (tag t) + x_t
    phase(0, t, 2, (unsigned)t, (t - 1) & 3, t, t > 0);
    asm volatile("s_waitcnt lgkmcnt(0)\n\ts_barrier" ::: "memory");
    // phase B: compute {2,3}(t); probe {0,1} r_t (tag t+1) + x_{t+1}
    phase(2, t, 0, (unsigned)(t + 1), t & 3, t + 1, t + 1 < T);
    asm volatile("s_waitcnt lgkmcnt(0)\n\ts_barrier" ::: "memory");
  }
}

// ---------------------------------------------------------------------------
// Readout: C[32768,72] = rate_all[32768,1024] x [h2o_w;h2o_ctx_w]^T + bias
// ---------------------------------------------------------------------------
__global__ __launch_bounds__(256) void rnn_readout(
    const float* __restrict__ rate_all,
    const float* __restrict__ h2o_w, const float* __restrict__ h2o_b,
    const float* __restrict__ h2o_ctx_w, const float* __restrict__ h2o_ctx_b,
    float* __restrict__ out0, float* __restrict__ out1)
{
  constexpr int RB = 128;
  constexpr int HC = 128;
  constexpr int SR = HC + 1;
  __shared__ float rl[RB * SR];
  __shared__ float wl[72 * SR];

  const int tid = threadIdx.x;
  const long long row0 = (long long)blockIdx.x * RB;
  const int rb = tid & 31, og = tid >> 5;

  float acc[4][9];
#pragma unroll
  for (int c = 0; c < 4; ++c)
#pragma unroll
    for (int i = 0; i < 9; ++i) acc[c][i] = 0.f;

  for (int hc = 0; hc < H / HC; ++hc) {
#pragma unroll
    for (int i = 0; i < 16; ++i) {
      const int q = i * 256 + tid;
      const int row = q >> 5, hq = q & 31;
      float4 v = *(const float4*)(rate_all + (row0 + row) * H + hc * HC + hq * 4);
      float* d = &rl[row * SR + hq * 4];
      d[0] = v.x; d[1] = v.y; d[2] = v.z; d[3] = v.w;
    }
#pragma unroll
    for (int i = 0; i < 9; ++i) {
      const int q = i * 256 + tid;
      const int o = q >> 5, hq = q & 31;
      const float* src = (o < OF) ? (h2o_w + (long long)o * H)
                                  : (h2o_ctx_w + (long long)(o - OF) * H);
      float4 v = *(const float4*)(src + hc * HC + hq * 4);
      float* d = &wl[o * SR + hq * 4];
      d[0] = v.x; d[1] = v.y; d[2] = v.z; d[3] = v.w;
    }
    __syncthreads();

#pragma unroll 4
    for (int h = 0; h < HC; ++h) {
      const float r0 = rl[(rb)      * SR + h];
      const float r1 = rl[(rb + 32) * SR + h];
      const float r2 = rl[(rb + 64) * SR + h];
      const float r3 = rl[(rb + 96) * SR + h];
#pragma unroll
      for (int i = 0; i < 9; ++i) {
        const float wv = wl[(og * 9 + i) * SR + h];
        acc[0][i] = fmaf(r0, wv, acc[0][i]);
        acc[1][i] = fmaf(r1, wv, acc[1][i]);
        acc[2][i] = fmaf(r2, wv, acc[2][i]);
        acc[3][i] = fmaf(r3, wv, acc[3][i]);
      }
    }
    __syncthreads();
  }

#pragma unroll
  for (int c = 0; c < 4; ++c) {
    const long long row = row0 + rb + 32 * c;
#pragma unroll
    for (int i = 0; i < 9; ++i) {
      const int o = og * 9 + i;
      if (o < OF) out0[row * OF + o] = acc[c][i] + h2o_b[o];
      else        out1[row * OC + (o - OF)] = acc[c][i] + h2o_ctx_b[o - OF];
    }
  }
}

extern "C" void kernel_launch(void* const* d_in, const int* in_sizes, int n_in,
                              void* d_out, int out_size, void* d_ws, size_t ws_size,
                              hipStream_t stream) {
  (void)in_sizes; (void)n_in; (void)d_ws; (void)ws_size; (void)out_size;
  const float* input_sig = (const float*)d_in[0];
  const float* rate0     = (const float*)d_in[1];
  const float* i2h_w     = (const float*)d_in[2];
  const float* i2h_b     = (const float*)d_in[3];
  const float* h2h_w     = (const float*)d_in[4];
  const float* h2h_b     = (const float*)d_in[5];
  const float* h2o_w     = (const float*)d_in[6];
  const float* h2o_b     = (const float*)d_in[7];
  const float* h2o_ctx_w = (const float*)d_in[8];
  const float* h2o_ctx_b = (const float*)d_in[9];

  float* out      = (float*)d_out;
  float* out0     = out;
  float* out1     = out + OUT1_OFF;
  float* rate_all = out + OUT2_OFF;
  // Tagged 4-slot ring in the first 1 MB of out0 (overwritten by readout).
  unsigned long long* ring = (unsigned long long*)d_out;

  // Zero the ring EVERY call: expected tags are >=1, so zero never matches;
  // stale tags from a previous call/graph-replay would otherwise alias.
  hipMemsetAsync(ring, 0, (size_t)RING_U64 * 8, stream);
  hipLaunchKernelGGL(rnn_recur, dim3(NG * NM), dim3(512), 0, stream,
                     input_sig, rate0, i2h_w, i2h_b, h2h_w, h2h_b,
                     rate_all, ring);
  hipLaunchKernelGGL(rnn_readout, dim3(256), dim3(256), 0, stream,
                     rate_all, h2o_w, h2o_b, h2o_ctx_w, h2o_ctx_b, out0, out1);
}

// Round 20
// 2369.559 us; speedup vs baseline: 1.5595x; 1.5595x over previous
//
#include <hip/hip_runtime.h>

typedef float v2f __attribute__((ext_vector_type(2)));
typedef float v4f __attribute__((ext_vector_type(4)));

constexpr int T  = 1024;
constexpr int B  = 32;
constexpr int I_ = 64;
constexpr int H  = 1024;
constexpr int OF = 64;
constexpr int OC = 8;
constexpr int NG = 16;   // groups (2 batches each)
constexpr int NM = 16;   // member WGs per group (64 rows each)
constexpr int CH  = 136; // per-lane contiguous k-chunk (1088/8)
constexpr int CHP = 140; // padded chunk stride (12*l8 mod 32 -> all banks)
constexpr int BSTR = 8 * CHP;
constexpr long long OUT1_OFF = (long long)T * B * OF;
constexpr long long OUT2_OFF = (long long)T * B * (OF + OC);
constexpr int RING_U64 = NG * 4 * 2 * 1024;  // [g][slot(4)][b][row] = 1 MB

// Agent-scope relaxed ops: global_{load,store} sc0 sc1 — bypass L1/L2,
// coherent at L3, fence-free. Proven (R2/R6/R10/R11/R14/R15/R16). sc0-only
// polling livelocks (R4/R5/R7) — never used.
__device__ __forceinline__ void st_agent_f32(float* p, float v) {
  __hip_atomic_store(p, v, __ATOMIC_RELAXED, __HIP_MEMORY_SCOPE_AGENT);
}
__device__ __forceinline__ void st_agent_u64(unsigned long long* p,
                                             unsigned long long v) {
  __hip_atomic_store(p, v, __ATOMIC_RELAXED, __HIP_MEMORY_SCOPE_AGENT);
}
__device__ __forceinline__ unsigned long long
ld_agent_u64(const unsigned long long* p) {
  return __hip_atomic_load(p, __ATOMIC_RELAXED, __HIP_MEMORY_SCOPE_AGENT);
}

// ---------------------------------------------------------------------------
// Recurrence: 256 persistent WGs x 512 threads (1/CU). BEST-KNOWN (R16):
// tagged 2-value u64 packets {u32 tag=t+1 | f32 val} in a 4-slot ring;
// the data load IS the sync. Ping-pong schedule:
//   issue L1 loads (b1 r_t) + x_t(b1)
//   C0(t): pk-FMA matvec b0, store packets (tag t+1, slot t&3)
//   check L1 (loads flew under C0) -> commit lds[1]; lgkm-only barrier
//   C1(t) first half; MID-PHASE L0 issue (one sched_barrier pin, R14's
//   proven dose); C1 second half + stores
//   check L0 -> commit lds[0]; lgkm-only barrier
// Lap-safety: 4-slot ring (reuse distance 4 steps); ordering carried by
// data dependence (observing a member's tag t+1 proves its slot-s read
// completed). Liveness: polls are the only waits, on unconditionally-stored
// monotone tags. Ring zeroed per call (tags >= 1 never match zero).
// R12/R13/R17/R18/R19 alternatives (phase-split, xp precompute, dual
// sampling, wave specialization, 4-batch slack) all regressed — this
// structure sits at its measured cross-CU communication floor ~2.3us/step.
// ---------------------------------------------------------------------------
__global__ __launch_bounds__(512, 2) void rnn_recur(
    const float* __restrict__ input_sig, const float* __restrict__ rate0,
    const float* __restrict__ i2h_w, const float* __restrict__ i2h_b,
    const float* __restrict__ h2h_w, const float* __restrict__ h2h_b,
    float* __restrict__ rate_all, unsigned long long* __restrict__ ring)
{
  const int tid = threadIdx.x;
  const int bid = blockIdx.x;
  const int g   = bid & (NG - 1);
  const int m   = bid >> 4;
  const int l8  = tid & 7;
  const int jrel = tid >> 3;
  const int j   = m * 64 + jrel;
  const int bG  = g * 2;

  __shared__ float lds[2][BSTR];   // [batch][padded chunks]

  // ---- stationary weights: 68 float2 = 136 fp32/thread
  v2f w2[68];
#pragma unroll
  for (int q = 0; q < 68; ++q) {
    const int k = l8 * CH + q * 2;
    w2[q] = (k < H) ? *(const v2f*)(h2h_w + (long long)j * H + k)
                    : *(const v2f*)(i2h_w + (long long)j * I_ + (k - H));
  }
  const float bsum = h2h_b[j] + i2h_b[j];
  const int posj = (j / CH) * CHP + (j % CH);

  // ---- init: r_{-1} = rate0 and x_0 for both batches (plain cached loads)
  {
    const int b = tid >> 8, u4 = tid & 255;
    const int k0 = u4 * 4, c = k0 / CH, off = k0 - c * CH;
    float4 v = *(const float4*)(rate0 + (long long)(bG + b) * H + k0);
    *(float4*)&lds[b][c * CHP + off] = v;
    if (tid < 32) {
      const int b2 = tid >> 4, iq = tid & 15;
      float4 u = *(const float4*)(input_sig + (long long)(bG + b2) * I_ + iq * 4);
      *(float4*)&lds[b2][7 * CHP + 72 + iq * 4] = u;
    }
  }
  __syncthreads();

  unsigned long long* ringG = ring + (long long)g * (4 * 2 * 1024);
  const int c_  = (2 * tid) / CH;
  const int off_ = 2 * tid - c_ * CH;

  // full compute for batch b at step t (used for phase 0)
  auto phase = [&](int b, int t) {
    const float* Rb = &lds[b][0];
    v2f acc2 = {0.f, 0.f};
#pragma unroll
    for (int q = 0; q < 34; ++q) {
      const v4f rv = *(const v4f*)&Rb[l8 * CHP + q * 4];
      const v2f rlo = __builtin_shufflevector(rv, rv, 0, 1);
      const v2f rhi = __builtin_shufflevector(rv, rv, 2, 3);
      acc2 = __builtin_elementwise_fma(w2[2 * q],     rlo, acc2);
      acc2 = __builtin_elementwise_fma(w2[2 * q + 1], rhi, acc2);
    }
    float acc = acc2.x + acc2.y;
    acc += __shfl_xor(acc, 4, 64);
    acc += __shfl_xor(acc, 2, 64);
    acc += __shfl_xor(acc, 1, 64);
    if (l8 == 0) {
      const float pre  = acc + bsum;
      const float rold = Rb[posj];
      const float rnew = 0.9f * rold + 0.1f * tanhf(pre);
      const unsigned long long pkt =
          ((unsigned long long)(unsigned)(t + 1) << 32) |
          (unsigned long long)__float_as_uint(rnew);
      st_agent_u64(&ringG[((long long)((t & 3) * 2 + b) << 10) + j], pkt);
      st_agent_f32(&rate_all[((long long)t * B + bG + b) * H + j], rnew);
    }
  };

  for (int t = 0; t < T; ++t) {
    // ---- early-issue L1: b1's r_t (slot (t-1)&3, tag t)
    unsigned long long v10 = 0, v11 = 0;
    float4 xv1;
    const bool have1 = (t > 0);
    const unsigned long long* p1 =
        &ringG[((long long)((((t - 1) & 3) * 2) + 1) << 10) + 2 * tid];
    if (have1) {
      v10 = ld_agent_u64(p1);
      v11 = ld_agent_u64(p1 + 1);
      if (tid < 16) {
        xv1 = *(const float4*)(input_sig +
            ((long long)t * B + bG + 1) * I_ + tid * 4);
      }
    }

    phase(0, t);   // C0(t): L1 loads fly under this

    if (have1) {
      const unsigned tag = (unsigned)t;
      while ((unsigned)(v10 >> 32) != tag || (unsigned)(v11 >> 32) != tag) {
        v10 = ld_agent_u64(p1);
        v11 = ld_agent_u64(p1 + 1);
      }
      *(float2*)&lds[1][c_ * CHP + off_] = make_float2(
          __uint_as_float((unsigned)v10), __uint_as_float((unsigned)v11));
      if (tid < 16) *(float4*)&lds[1][7 * CHP + 72 + tid * 4] = xv1;
    }
    // mid-step barrier: LDS-drain only (stores keep flying)
    asm volatile("s_waitcnt lgkmcnt(0)\n\ts_barrier" ::: "memory");
    __builtin_amdgcn_sched_barrier(0);

    // ---- C1(t) inline, with MID-PHASE L0 issue ------------------------
    const float* Rb = &lds[1][0];
    v2f acc2 = {0.f, 0.f};
#pragma unroll
    for (int q = 0; q < 17; ++q) {            // first half
      const v4f rv = *(const v4f*)&Rb[l8 * CHP + q * 4];
      const v2f rlo = __builtin_shufflevector(rv, rv, 0, 1);
      const v2f rhi = __builtin_shufflevector(rv, rv, 2, 3);
      acc2 = __builtin_elementwise_fma(w2[2 * q],     rlo, acc2);
      acc2 = __builtin_elementwise_fma(w2[2 * q + 1], rhi, acc2);
    }
    // mid-phase probe: samples L3 ~0.4us after C0's stores (past visibility)
    unsigned long long v00 = 0, v01 = 0;
    float4 xv0;
    const bool have0 = (t + 1 < T);
    const unsigned long long* p0 =
        &ringG[((long long)((t & 3) * 2) << 10) + 2 * tid];
    if (have0) {
      v00 = ld_agent_u64(p0);
      v01 = ld_agent_u64(p0 + 1);
      if (tid < 16) {
        xv0 = *(const float4*)(input_sig +
            ((long long)(t + 1) * B + bG) * I_ + tid * 4);
      }
    }
    __builtin_amdgcn_sched_barrier(0);        // pin the probe issue point
#pragma unroll
    for (int q = 17; q < 34; ++q) {           // second half
      const v4f rv = *(const v4f*)&Rb[l8 * CHP + q * 4];
      const v2f rlo = __builtin_shufflevector(rv, rv, 0, 1);
      const v2f rhi = __builtin_shufflevector(rv, rv, 2, 3);
      acc2 = __builtin_elementwise_fma(w2[2 * q],     rlo, acc2);
      acc2 = __builtin_elementwise_fma(w2[2 * q + 1], rhi, acc2);
    }
    float acc = acc2.x + acc2.y;
    acc += __shfl_xor(acc, 4, 64);
    acc += __shfl_xor(acc, 2, 64);
    acc += __shfl_xor(acc, 1, 64);
    if (l8 == 0) {
      const float pre  = acc + bsum;
      const float rold = Rb[posj];
      const float rnew = 0.9f * rold + 0.1f * tanhf(pre);
      const unsigned long long pkt =
          ((unsigned long long)(unsigned)(t + 1) << 32) |
          (unsigned long long)__float_as_uint(rnew);
      st_agent_u64(&ringG[((long long)((t & 3) * 2 + 1) << 10) + j], pkt);
      st_agent_f32(&rate_all[((long long)t * B + bG + 1) * H + j], rnew);
    }

    if (have0) {
      const unsigned tag = (unsigned)(t + 1);
      while ((unsigned)(v00 >> 32) != tag || (unsigned)(v01 >> 32) != tag) {
        v00 = ld_agent_u64(p0);
        v01 = ld_agent_u64(p0 + 1);
      }
      *(float2*)&lds[0][c_ * CHP + off_] = make_float2(
          __uint_as_float((unsigned)v00), __uint_as_float((unsigned)v01));
      if (tid < 16) *(float4*)&lds[0][7 * CHP + 72 + tid * 4] = xv0;
    }
    // end-of-step barrier: LDS-drain only — NO vmcnt drain (4-slot ring
    // makes same-address store ordering structural)
    asm volatile("s_waitcnt lgkmcnt(0)\n\ts_barrier" ::: "memory");
    __builtin_amdgcn_sched_barrier(0);
  }
}

// ---------------------------------------------------------------------------
// Readout: C[32768,72] = rate_all[32768,1024] x [h2o_w;h2o_ctx_w]^T + bias
// ---------------------------------------------------------------------------
__global__ __launch_bounds__(256) void rnn_readout(
    const float* __restrict__ rate_all,
    const float* __restrict__ h2o_w, const float* __restrict__ h2o_b,
    const float* __restrict__ h2o_ctx_w, const float* __restrict__ h2o_ctx_b,
    float* __restrict__ out0, float* __restrict__ out1)
{
  constexpr int RB = 128;
  constexpr int HC = 128;
  constexpr int SR = HC + 1;
  __shared__ float rl[RB * SR];
  __shared__ float wl[72 * SR];

  const int tid = threadIdx.x;
  const long long row0 = (long long)blockIdx.x * RB;
  const int rb = tid & 31, og = tid >> 5;

  float acc[4][9];
#pragma unroll
  for (int c = 0; c < 4; ++c)
#pragma unroll
    for (int i = 0; i < 9; ++i) acc[c][i] = 0.f;

  for (int hc = 0; hc < H / HC; ++hc) {
#pragma unroll
    for (int i = 0; i < 16; ++i) {
      const int q = i * 256 + tid;
      const int row = q >> 5, hq = q & 31;
      float4 v = *(const float4*)(rate_all + (row0 + row) * H + hc * HC + hq * 4);
      float* d = &rl[row * SR + hq * 4];
      d[0] = v.x; d[1] = v.y; d[2] = v.z; d[3] = v.w;
    }
#pragma unroll
    for (int i = 0; i < 9; ++i) {
      const int q = i * 256 + tid;
      const int o = q >> 5, hq = q & 31;
      const float* src = (o < OF) ? (h2o_w + (long long)o * H)
                                  : (h2o_ctx_w + (long long)(o - OF) * H);
      float4 v = *(const float4*)(src + hc * HC + hq * 4);
      float* d = &wl[o * SR + hq * 4];
      d[0] = v.x; d[1] = v.y; d[2] = v.z; d[3] = v.w;
    }
    __syncthreads();

#pragma unroll 4
    for (int h = 0; h < HC; ++h) {
      const float r0 = rl[(rb)      * SR + h];
      const float r1 = rl[(rb + 32) * SR + h];
      const float r2 = rl[(rb + 64) * SR + h];
      const float r3 = rl[(rb + 96) * SR + h];
#pragma unroll
      for (int i = 0; i < 9; ++i) {
        const float wv = wl[(og * 9 + i) * SR + h];
        acc[0][i] = fmaf(r0, wv, acc[0][i]);
        acc[1][i] = fmaf(r1, wv, acc[1][i]);
        acc[2][i] = fmaf(r2, wv, acc[2][i]);
        acc[3][i] = fmaf(r3, wv, acc[3][i]);
      }
    }
    __syncthreads();
  }

#pragma unroll
  for (int c = 0; c < 4; ++c) {
    const long long row = row0 + rb + 32 * c;
#pragma unroll
    for (int i = 0; i < 9; ++i) {
      const int o = og * 9 + i;
      if (o < OF) out0[row * OF + o] = acc[c][i] + h2o_b[o];
      else        out1[row * OC + (o - OF)] = acc[c][i] + h2o_ctx_b[o - OF];
    }
  }
}

extern "C" void kernel_launch(void* const* d_in, const int* in_sizes, int n_in,
                              void* d_out, int out_size, void* d_ws, size_t ws_size,
                              hipStream_t stream) {
  (void)in_sizes; (void)n_in; (void)d_ws; (void)ws_size; (void)out_size;
  const float* input_sig = (const float*)d_in[0];
  const float* rate0     = (const float*)d_in[1];
  const float* i2h_w     = (const float*)d_in[2];
  const float* i2h_b     = (const float*)d_in[3];
  const float* h2h_w     = (const float*)d_in[4];
  const float* h2h_b     = (const float*)d_in[5];
  const float* h2o_w     = (const float*)d_in[6];
  const float* h2o_b     = (const float*)d_in[7];
  const float* h2o_ctx_w = (const float*)d_in[8];
  const float* h2o_ctx_b = (const float*)d_in[9];

  float* out      = (float*)d_out;
  float* out0     = out;
  float* out1     = out + OUT1_OFF;
  float* rate_all = out + OUT2_OFF;
  // Tagged 4-slot ring in the first 1 MB of out0 (overwritten by readout).
  unsigned long long* ring = (unsigned long long*)d_out;

  // Zero the ring EVERY call: expected tags are >=1, so zero never matches;
  // stale tags from a previous call/graph-replay would otherwise alias.
  hipMemsetAsync(ring, 0, (size_t)RING_U64 * 8, stream);
  hipLaunchKernelGGL(rnn_recur, dim3(NG * NM), dim3(512), 0, stream,
                     input_sig, rate0, i2h_w, i2h_b, h2h_w, h2h_b,
                     rate_all, ring);
  hipLaunchKernelGGL(rnn_readout, dim3(256), dim3(256), 0, stream,
                     rate_all, h2o_w, h2o_b, h2o_ctx_w, h2o_ctx_b, out0, out1);
}